// Round 7
// baseline (173.656 us; speedup 1.0000x reference)
//
#include <hip/hip_runtime.h>
#include <stdint.h>

#define N_ROWS 4096
#define N_DIM  2048
#define MARGIN 0.3f
#define NTILE  32            // 4096 / 128 tiles per side
#define NITER  (N_DIM / 64)  // BK=64 -> 32 K-iterations
#define FLTMAX 3.402823466e+38f

typedef __attribute__((ext_vector_type(8))) short short8;
typedef __attribute__((ext_vector_type(4))) float floatx4;

// Packed layout ("fragment order"): for 16-row group b (256 total) and k-chunk
// c (32 k, 64 total), a 1 KB block at shorts-offset (b*64+c)*512. Lane l's
// 16 B fragment at l*8 shorts = row b*16+(l&15), k c*32+(l>>4)*8.. (verified
// absmax 0.0 in R1-R6). A BK=64 iter `it` uses chunks {2it, 2it+1}, which are
// CONTIGUOUS 2 KB per row-group b -> staging is a linear memcpy.

__device__ inline unsigned short f2bf_rne(float f) {
  unsigned u = __float_as_uint(f);
  unsigned r = 0x7fffu + ((u >> 16) & 1u);
  return (unsigned short)((u + r) >> 16);
}
__device__ inline float bf2f(unsigned short h) {
  return __uint_as_float(((unsigned)h) << 16);
}

// ---------------------------------------------------------------------------
// Kernel 1: cast fp32 -> bf16 AND repack into fragment order; sq[i] from the
// ROUNDED values; init per-row reduction cells. One block per 16-row group.
// ---------------------------------------------------------------------------
__global__ __launch_bounds__(256) void prep_kernel(
    const float* __restrict__ X, unsigned short* __restrict__ Xp,
    float* __restrict__ sq, unsigned* __restrict__ ap, unsigned* __restrict__ an)
{
  const int b = blockIdx.x;
  const int t = threadIdx.x;
  const int r = t & 15, j = (t >> 4) & 3, w = t >> 6;
  const float* Xg = X + ((size_t)b * 16 + r) * N_DIM + j * 8;
  unsigned short* Op = Xp + (size_t)b * 64 * 512 + (size_t)(j * 16 + r) * 8;
  float acc = 0.f;
#pragma unroll
  for (int s = 0; s < 16; ++s) {
    const int c = w + s * 4;
    float4 v0 = *(const float4*)(Xg + c * 32);
    float4 v1 = *(const float4*)(Xg + c * 32 + 4);
    short8 o;
    o[0] = (short)f2bf_rne(v0.x); o[1] = (short)f2bf_rne(v0.y);
    o[2] = (short)f2bf_rne(v0.z); o[3] = (short)f2bf_rne(v0.w);
    o[4] = (short)f2bf_rne(v1.x); o[5] = (short)f2bf_rne(v1.y);
    o[6] = (short)f2bf_rne(v1.z); o[7] = (short)f2bf_rne(v1.w);
#pragma unroll
    for (int e = 0; e < 8; ++e) {
      float f = bf2f((unsigned short)o[e]);
      acc = fmaf(f, f, acc);
    }
    *(short8*)(Op + (size_t)c * 512) = o;
  }
  acc += __shfl_xor(acc, 16, 64);
  acc += __shfl_xor(acc, 32, 64);
  __shared__ float part[4][16];
  if ((t & 63) < 16) part[w][r] = acc;
  __syncthreads();
  if (t < 16) {
    float s4 = part[0][t] + part[1][t] + part[2][t] + part[3][t];
    sq[b * 16 + t] = s4;
    ap[b * 16 + t] = 0u;           // max identity (dist >= 0)
    an[b * 16 + t] = 0x7f7fffffu;  // FLT_MAX bits
  }
}

// ---------------------------------------------------------------------------
// Kernel 2: upper-triangle 128x128 tiles, classic LDS GEMM rebuilt on the
// packed array. R5 was L2-BW-bound (2.06 GB issued = 84% of L2 ceiling, each
// fragment loaded by 2 waves); LDS staging fetches each tile byte from L2
// ONCE (0.55 GB) and fans out via the independent LDS pipe. R4's two fatal
// flaws fixed: staging loads are now fully-coalesced linear sweeps (packed
// layout: 64 B/thread contiguous, 2 KB/segment), and the double buffer needs
// only ONE barrier/iter (write buf nxt while reading buf cur; end-of-iter
// barrier orders both hazards). No forced min-waves (R6 spill lesson).
// Each wave's 64x64 output feeds row-side AND (symmetry) col-side reductions.
// ---------------------------------------------------------------------------
__global__ __launch_bounds__(256, 2) void dist_kernel(
    const unsigned short* __restrict__ Xp, const float* __restrict__ sq,
    const int* __restrict__ lab, unsigned* __restrict__ ap, unsigned* __restrict__ an)
{
  __shared__ __align__(16) unsigned short As[2][8192];   // 2 x 16 KB
  __shared__ __align__(16) unsigned short Bs[2][8192];   // 2 x 16 KB
  __shared__ float sqi[128], sqj[128];
  __shared__ int labi[128], labj[128];

  // decode linear block id -> (bi, bj) with bi <= bj
  int p = blockIdx.x;
  int bi = 0;
  while (p >= NTILE - bi) { p -= NTILE - bi; ++bi; }
  const int bj = bi + p;
  const bool offdiag = (bi != bj);

  const int t = threadIdx.x;
  const int lane = t & 63, w = t >> 6;     // 4 waves
  const int wm = w >> 1, wn = w & 1;       // 2x2 wave grid, 64x64 per wave

  if (t < 128) { int rr = bi * 128 + t; sqi[t] = sq[rr]; labi[t] = lab[rr]; }
  else         { int cc = bj * 128 + (t - 128); sqj[t - 128] = sq[cc]; labj[t - 128] = lab[cc]; }

  // staging map: thread t -> segment seg = t>>5 (row-group), 64 B at sub*64.
  // global (shorts): ((bX*8+seg)*64 + 2*it)*512 + sub*32 ; iter stride 1024.
  // lds    (shorts): seg*1024 + sub*32  (slot layout (rg*2+c)*512 preserved
  // by the linear copy since global chunk order within the 2 KB == lds order).
  const int seg = t >> 5, sub = t & 31;
  const unsigned gA0 = ((unsigned)(bi * 8 + seg) * 64) * 512 + sub * 32;
  const unsigned gB0 = ((unsigned)(bj * 8 + seg) * 64) * 512 + sub * 32;
  const unsigned lofs = (unsigned)seg * 1024 + sub * 32;

  short8 ra[4], rb[4];
#define LOADG(IT)                                                            \
  do {                                                                       \
    _Pragma("unroll")                                                        \
    for (int q = 0; q < 4; ++q) {                                            \
      ra[q] = *(const short8*)(Xp + gA0 + (unsigned)(IT) * 1024 + q * 8);    \
      if (offdiag) rb[q] = *(const short8*)(Xp + gB0 + (unsigned)(IT) * 1024 + q * 8); \
    }                                                                        \
  } while (0)
#define STORE(BUF)                                                           \
  do {                                                                       \
    _Pragma("unroll")                                                        \
    for (int q = 0; q < 4; ++q) {                                            \
      *(short8*)&As[BUF][lofs + q * 8] = ra[q];                              \
      if (offdiag) *(short8*)&Bs[BUF][lofs + q * 8] = rb[q];                 \
    }                                                                        \
  } while (0)

  LOADG(0);
  STORE(0);
  __syncthreads();                         // tile 0 + sqi/sqj visible

  floatx4 acc[4][4] = {};

  for (int it = 0; it < NITER; ++it) {
    const int cur = it & 1;
    const bool has_next = (it + 1 < NITER);
    if (has_next) LOADG(it + 1);           // global->VGPR, overlaps compute

    const unsigned short* Asrc = As[cur];
    const unsigned short* Bsrc = offdiag ? Bs[cur] : As[cur];
#pragma unroll
    for (int kh = 0; kh < 2; ++kh) {
      short8 af[4], bfv[4];
#pragma unroll
      for (int mi = 0; mi < 4; ++mi)
        af[mi] = *(const short8*)&Asrc[((wm * 4 + mi) * 2 + kh) * 512 + lane * 8];
#pragma unroll
      for (int ni = 0; ni < 4; ++ni)
        bfv[ni] = *(const short8*)&Bsrc[((wn * 4 + ni) * 2 + kh) * 512 + lane * 8];
#pragma unroll
      for (int mi = 0; mi < 4; ++mi)
#pragma unroll
        for (int ni = 0; ni < 4; ++ni)
          acc[mi][ni] = __builtin_amdgcn_mfma_f32_16x16x32_bf16(
              af[mi], bfv[ni], acc[mi][ni], 0, 0, 0);
    }

    if (has_next) {
      STORE(cur ^ 1);      // other buffer: no hazard with this iter's reads
      __syncthreads();     // orders: my writes vis. next iter; reads done before overwrite
    }
  }
#undef LOADG
#undef STORE

  // Epilogue. C/D layout (m89): col = lane&15, row = (lane>>4)*4 + reg.
  const int cn = lane & 15, lg = lane >> 4;
  float sqc[4]; int labc[4];
#pragma unroll
  for (int ni = 0; ni < 4; ++ni) {
    int c = wn * 64 + ni * 16 + cn;
    sqc[ni] = sqj[c]; labc[ni] = labj[c];
  }
  float cap[4] = {0.f, 0.f, 0.f, 0.f};
  float can[4] = {FLTMAX, FLTMAX, FLTMAX, FLTMAX};
#pragma unroll
  for (int mi = 0; mi < 4; ++mi) {
#pragma unroll
    for (int r = 0; r < 4; ++r) {
      const int rl = wm * 64 + mi * 16 + lg * 4 + r;   // row within 128-tile
      const float si = sqi[rl];
      const int li = labi[rl];
      float apv = 0.0f;
      float anv = FLTMAX;
#pragma unroll
      for (int ni = 0; ni < 4; ++ni) {
        float g = acc[mi][ni][r];
        float d2 = fmaf(-2.0f, g, si + sqc[ni]);
        d2 = fmaxf(d2, 1e-12f);
        float d = __builtin_amdgcn_sqrtf(d2);
        const bool same = (li == labc[ni]);
        const float dp = same ? d : 0.0f;
        const float dn = same ? FLTMAX : d;
        apv = fmaxf(apv, dp);
        anv = fminf(anv, dn);
        cap[ni] = fmaxf(cap[ni], dp);   // col-side (symmetric) partials
        can[ni] = fminf(can[ni], dn);
      }
      // row side: reduce over the 16 cn-lanes (same lg = same row)
#pragma unroll
      for (int m = 8; m >= 1; m >>= 1) {
        apv = fmaxf(apv, __shfl_xor(apv, m, 64));
        anv = fminf(anv, __shfl_xor(anv, m, 64));
      }
      if (cn == 0) {
        int R = bi * 128 + rl;
        atomicMax(&ap[R], __float_as_uint(apv));
        atomicMin(&an[R], __float_as_uint(anv));
      }
    }
  }
  // col side: reduce over lg (xor 16,32) -> full 64 rows per column
#pragma unroll
  for (int ni = 0; ni < 4; ++ni) {
    float a = cap[ni], b = can[ni];
#pragma unroll
    for (int m = 16; m <= 32; m <<= 1) {
      a = fmaxf(a, __shfl_xor(a, m, 64));
      b = fminf(b, __shfl_xor(b, m, 64));
    }
    if (lg == 0) {
      int C = bj * 128 + wn * 64 + ni * 16 + cn;
      atomicMax(&ap[C], __float_as_uint(a));
      atomicMin(&an[C], __float_as_uint(b));
    }
  }
}

// ---------------------------------------------------------------------------
// Kernel 3: loss = mean(relu(margin + dist_ap - dist_an))
// ---------------------------------------------------------------------------
__global__ __launch_bounds__(256) void finalize_kernel(
    const unsigned* __restrict__ ap, const unsigned* __restrict__ an,
    float* __restrict__ out)
{
  const int t = threadIdx.x;
  float s = 0.f;
  for (int i = t; i < N_ROWS; i += 256) {
    float a = __uint_as_float(ap[i]);
    float b = __uint_as_float(an[i]);
    s += fmaxf(MARGIN + a - b, 0.0f);
  }
#pragma unroll
  for (int m = 32; m >= 1; m >>= 1) s += __shfl_down(s, m, 64);
  __shared__ float wsum[4];
  const int lane = t & 63, w = t >> 6;
  if (lane == 0) wsum[w] = s;
  __syncthreads();
  if (t == 0) out[0] = (wsum[0] + wsum[1] + wsum[2] + wsum[3]) * (1.0f / N_ROWS);
}

extern "C" void kernel_launch(void* const* d_in, const int* in_sizes, int n_in,
                              void* d_out, int out_size, void* d_ws, size_t ws_size,
                              hipStream_t stream) {
  const float* X = (const float*)d_in[0];
  const int* lab = (const int*)d_in[1];
  float* out = (float*)d_out;

  char* ws = (char*)d_ws;
  unsigned short* Xp = (unsigned short*)ws;                           // 16 MB packed
  float* sq  = (float*)(ws + (size_t)N_ROWS * N_DIM * 2);             // 16 KB
  unsigned* ap = (unsigned*)((char*)sq + N_ROWS * sizeof(float));     // 16 KB
  unsigned* an = (unsigned*)((char*)ap + N_ROWS * sizeof(unsigned));  // 16 KB

  prep_kernel<<<N_ROWS / 16, 256, 0, stream>>>(X, Xp, sq, ap, an);
  dist_kernel<<<NTILE * (NTILE + 1) / 2, 256, 0, stream>>>(Xp, sq, lab, ap, an);
  finalize_kernel<<<1, 256, 0, stream>>>(ap, an, out);
}

// Round 8
// 147.963 us; speedup vs baseline: 1.1736x; 1.1736x over previous
//
#include <hip/hip_runtime.h>
#include <stdint.h>

#define N_ROWS 4096
#define N_DIM  2048
#define MARGIN 0.3f
#define NTILE  32            // 4096 / 128 tiles per side
#define NITER  (N_DIM / 64)  // BK=64 -> 32 K-iterations
#define FLTMAX 3.402823466e+38f

typedef __attribute__((ext_vector_type(8))) short short8;
typedef __attribute__((ext_vector_type(4))) float floatx4;

// Packed layout ("fragment order"): for 16-row group b (256 total) and k-chunk
// c (32 k, 64 total), a 1 KB block at shorts-offset (b*64+c)*512. Lane l's
// 16 B fragment at l*8 shorts = row b*16+(l&15), k c*32+(l>>4)*8.. (verified
// absmax 0.0 in R1-R7). A BK=64 iter uses k-chunks {2it,2it+1}: contiguous
// 2 KB per row-group.

__device__ inline unsigned short f2bf_rne(float f) {
  unsigned u = __float_as_uint(f);
  unsigned r = 0x7fffu + ((u >> 16) & 1u);
  return (unsigned short)((u + r) >> 16);
}
__device__ inline float bf2f(unsigned short h) {
  return __uint_as_float(((unsigned)h) << 16);
}

// ---------------------------------------------------------------------------
// Kernel 1: cast fp32 -> bf16 AND repack into fragment order; sq[i] from the
// ROUNDED values; init per-row reduction cells. One block per 16-row group.
// ---------------------------------------------------------------------------
__global__ __launch_bounds__(256) void prep_kernel(
    const float* __restrict__ X, unsigned short* __restrict__ Xp,
    float* __restrict__ sq, unsigned* __restrict__ ap, unsigned* __restrict__ an)
{
  const int b = blockIdx.x;
  const int t = threadIdx.x;
  const int r = t & 15, j = (t >> 4) & 3, w = t >> 6;
  const float* Xg = X + ((size_t)b * 16 + r) * N_DIM + j * 8;
  unsigned short* Op = Xp + (size_t)b * 64 * 512 + (size_t)(j * 16 + r) * 8;
  float acc = 0.f;
#pragma unroll
  for (int s = 0; s < 16; ++s) {
    const int c = w + s * 4;
    float4 v0 = *(const float4*)(Xg + c * 32);
    float4 v1 = *(const float4*)(Xg + c * 32 + 4);
    short8 o;
    o[0] = (short)f2bf_rne(v0.x); o[1] = (short)f2bf_rne(v0.y);
    o[2] = (short)f2bf_rne(v0.z); o[3] = (short)f2bf_rne(v0.w);
    o[4] = (short)f2bf_rne(v1.x); o[5] = (short)f2bf_rne(v1.y);
    o[6] = (short)f2bf_rne(v1.z); o[7] = (short)f2bf_rne(v1.w);
#pragma unroll
    for (int e = 0; e < 8; ++e) {
      float f = bf2f((unsigned short)o[e]);
      acc = fmaf(f, f, acc);
    }
    *(short8*)(Op + (size_t)c * 512) = o;
  }
  acc += __shfl_xor(acc, 16, 64);
  acc += __shfl_xor(acc, 32, 64);
  __shared__ float part[4][16];
  if ((t & 63) < 16) part[w][r] = acc;
  __syncthreads();
  if (t < 16) {
    float s4 = part[0][t] + part[1][t] + part[2][t] + part[3][t];
    sq[b * 16 + t] = s4;
    ap[b * 16 + t] = 0u;           // max identity (dist >= 0)
    an[b * 16 + t] = 0x7f7fffffu;  // FLT_MAX bits
  }
}

// ---------------------------------------------------------------------------
// Kernel 2: upper-triangle 128x128 tiles, LDS GEMM on the packed array.
// R7 fix: staging uses the IDENTITY chunk map c = q*256 + t. LDS write addr
// = c*16 B (16 B lane-stride -> 2-way bank aliasing = free, m136). Global
// source: seg = c>>7 (row-group), off16 = c&127 -> each wave's load is one
// contiguous 1 KB read of the packed array (coalesced). Double-buffered,
// ONE barrier per iter. Each wave's 64x64 output feeds row-side AND
// (symmetry) col-side hardest-pos/neg reductions.
// ---------------------------------------------------------------------------
__global__ __launch_bounds__(256, 2) void dist_kernel(
    const unsigned short* __restrict__ Xp, const float* __restrict__ sq,
    const int* __restrict__ lab, unsigned* __restrict__ ap, unsigned* __restrict__ an)
{
  __shared__ __align__(16) unsigned short As[2][8192];   // 2 x 16 KB
  __shared__ __align__(16) unsigned short Bs[2][8192];   // 2 x 16 KB
  __shared__ float sqi[128], sqj[128];
  __shared__ int labi[128], labj[128];

  // decode linear block id -> (bi, bj) with bi <= bj
  int p = blockIdx.x;
  int bi = 0;
  while (p >= NTILE - bi) { p -= NTILE - bi; ++bi; }
  const int bj = bi + p;
  const bool offdiag = (bi != bj);

  const int t = threadIdx.x;
  const int lane = t & 63, w = t >> 6;     // 4 waves
  const int wm = w >> 1, wn = w & 1;       // 2x2 wave grid, 64x64 per wave

  if (t < 128) { int rr = bi * 128 + t; sqi[t] = sq[rr]; labi[t] = lab[rr]; }
  else         { int cc = bj * 128 + (t - 128); sqj[t - 128] = sq[cc]; labj[t - 128] = lab[cc]; }

  // identity chunk map: chunk c = q*256 + t (q = 0..3), 16 B per chunk.
  // LDS shorts offset: c*8. Global shorts offset: ((bX*8 + (c>>7))*64)*512
  // + (c&127)*8, plus it*1024 per K-iter.
  unsigned gA[4], gB[4], lo[4];
#pragma unroll
  for (int q = 0; q < 4; ++q) {
    const unsigned c = q * 256 + t;
    const unsigned seg = c >> 7, off16 = c & 127;
    gA[q] = ((unsigned)(bi * 8 + seg) * 64) * 512 + off16 * 8;
    gB[q] = ((unsigned)(bj * 8 + seg) * 64) * 512 + off16 * 8;
    lo[q] = c * 8;
  }

  short8 ra[4], rb[4];
#define LOADG(IT)                                                            \
  do {                                                                       \
    _Pragma("unroll")                                                        \
    for (int q = 0; q < 4; ++q) {                                            \
      ra[q] = *(const short8*)(Xp + gA[q] + (unsigned)(IT) * 1024);          \
      if (offdiag) rb[q] = *(const short8*)(Xp + gB[q] + (unsigned)(IT) * 1024); \
    }                                                                        \
  } while (0)
#define STORE(BUF)                                                           \
  do {                                                                       \
    _Pragma("unroll")                                                        \
    for (int q = 0; q < 4; ++q) {                                            \
      *(short8*)&As[BUF][lo[q]] = ra[q];                                     \
      if (offdiag) *(short8*)&Bs[BUF][lo[q]] = rb[q];                        \
    }                                                                        \
  } while (0)

  LOADG(0);
  STORE(0);
  __syncthreads();                         // tile 0 + sqi/sqj visible

  floatx4 acc[4][4] = {};

  for (int it = 0; it < NITER; ++it) {
    const int cur = it & 1;
    const bool has_next = (it + 1 < NITER);
    if (has_next) LOADG(it + 1);           // global->VGPR, overlaps compute

    const unsigned short* Asrc = As[cur];
    const unsigned short* Bsrc = offdiag ? Bs[cur] : As[cur];
#pragma unroll
    for (int kh = 0; kh < 2; ++kh) {
      short8 af[4], bfv[4];
#pragma unroll
      for (int mi = 0; mi < 4; ++mi)
        af[mi] = *(const short8*)&Asrc[((wm * 4 + mi) * 2 + kh) * 512 + lane * 8];
#pragma unroll
      for (int ni = 0; ni < 4; ++ni)
        bfv[ni] = *(const short8*)&Bsrc[((wn * 4 + ni) * 2 + kh) * 512 + lane * 8];
#pragma unroll
      for (int mi = 0; mi < 4; ++mi)
#pragma unroll
        for (int ni = 0; ni < 4; ++ni)
          acc[mi][ni] = __builtin_amdgcn_mfma_f32_16x16x32_bf16(
              af[mi], bfv[ni], acc[mi][ni], 0, 0, 0);
    }

    if (has_next) {
      STORE(cur ^ 1);      // other buffer: no hazard with this iter's reads
      __syncthreads();     // writes visible next iter; reads done before overwrite
    }
  }
#undef LOADG
#undef STORE

  // Epilogue. C/D layout (m89): col = lane&15, row = (lane>>4)*4 + reg.
  const int cn = lane & 15, lg = lane >> 4;
  float sqc[4]; int labc[4];
#pragma unroll
  for (int ni = 0; ni < 4; ++ni) {
    int c = wn * 64 + ni * 16 + cn;
    sqc[ni] = sqj[c]; labc[ni] = labj[c];
  }
  float cap[4] = {0.f, 0.f, 0.f, 0.f};
  float can[4] = {FLTMAX, FLTMAX, FLTMAX, FLTMAX};
#pragma unroll
  for (int mi = 0; mi < 4; ++mi) {
#pragma unroll
    for (int r = 0; r < 4; ++r) {
      const int rl = wm * 64 + mi * 16 + lg * 4 + r;   // row within 128-tile
      const float si = sqi[rl];
      const int li = labi[rl];
      float apv = 0.0f;
      float anv = FLTMAX;
#pragma unroll
      for (int ni = 0; ni < 4; ++ni) {
        float g = acc[mi][ni][r];
        float d2 = fmaf(-2.0f, g, si + sqc[ni]);
        d2 = fmaxf(d2, 1e-12f);
        float d = __builtin_amdgcn_sqrtf(d2);
        const bool same = (li == labc[ni]);
        const float dp = same ? d : 0.0f;
        const float dn = same ? FLTMAX : d;
        apv = fmaxf(apv, dp);
        anv = fminf(anv, dn);
        cap[ni] = fmaxf(cap[ni], dp);   // col-side (symmetric) partials
        can[ni] = fminf(can[ni], dn);
      }
      // row side: reduce over the 16 cn-lanes (same lg = same row)
#pragma unroll
      for (int m = 8; m >= 1; m >>= 1) {
        apv = fmaxf(apv, __shfl_xor(apv, m, 64));
        anv = fminf(anv, __shfl_xor(anv, m, 64));
      }
      if (cn == 0) {
        int R = bi * 128 + rl;
        atomicMax(&ap[R], __float_as_uint(apv));
        atomicMin(&an[R], __float_as_uint(anv));
      }
    }
  }
  // col side: reduce over lg (xor 16,32) -> full 64 rows per column
#pragma unroll
  for (int ni = 0; ni < 4; ++ni) {
    float a = cap[ni], b = can[ni];
#pragma unroll
    for (int m = 16; m <= 32; m <<= 1) {
      a = fmaxf(a, __shfl_xor(a, m, 64));
      b = fminf(b, __shfl_xor(b, m, 64));
    }
    if (lg == 0) {
      int C = bj * 128 + wn * 64 + ni * 16 + cn;
      atomicMax(&ap[C], __float_as_uint(a));
      atomicMin(&an[C], __float_as_uint(b));
    }
  }
}

// ---------------------------------------------------------------------------
// Kernel 3: loss = mean(relu(margin + dist_ap - dist_an))
// ---------------------------------------------------------------------------
__global__ __launch_bounds__(256) void finalize_kernel(
    const unsigned* __restrict__ ap, const unsigned* __restrict__ an,
    float* __restrict__ out)
{
  const int t = threadIdx.x;
  float s = 0.f;
  for (int i = t; i < N_ROWS; i += 256) {
    float a = __uint_as_float(ap[i]);
    float b = __uint_as_float(an[i]);
    s += fmaxf(MARGIN + a - b, 0.0f);
  }
#pragma unroll
  for (int m = 32; m >= 1; m >>= 1) s += __shfl_down(s, m, 64);
  __shared__ float wsum[4];
  const int lane = t & 63, w = t >> 6;
  if (lane == 0) wsum[w] = s;
  __syncthreads();
  if (t == 0) out[0] = (wsum[0] + wsum[1] + wsum[2] + wsum[3]) * (1.0f / N_ROWS);
}

extern "C" void kernel_launch(void* const* d_in, const int* in_sizes, int n_in,
                              void* d_out, int out_size, void* d_ws, size_t ws_size,
                              hipStream_t stream) {
  const float* X = (const float*)d_in[0];
  const int* lab = (const int*)d_in[1];
  float* out = (float*)d_out;

  char* ws = (char*)d_ws;
  unsigned short* Xp = (unsigned short*)ws;                           // 16 MB packed
  float* sq  = (float*)(ws + (size_t)N_ROWS * N_DIM * 2);             // 16 KB
  unsigned* ap = (unsigned*)((char*)sq + N_ROWS * sizeof(float));     // 16 KB
  unsigned* an = (unsigned*)((char*)ap + N_ROWS * sizeof(unsigned));  // 16 KB

  prep_kernel<<<N_ROWS / 16, 256, 0, stream>>>(X, Xp, sq, ap, an);
  dist_kernel<<<NTILE * (NTILE + 1) / 2, 256, 0, stream>>>(Xp, sq, lab, ap, an);
  finalize_kernel<<<1, 256, 0, stream>>>(ap, an, out);
}